// Round 13
// baseline (1143.856 us; speedup 1.0000x reference)
//
#include <hip/hip_runtime.h>
#include <limits.h>

// Problem constants (fixed by the reference: LATTICE=(4096,4096), N_CLUSTERS=262144)
#define N_SITES   (4096 * 4096)      // 16,777,216
#define N_LABELS  262144
#define NWORDS    (N_SITES / 32)     // 524,288 bitmap words
#define NSEENW    (N_LABELS / 32)    // 8,192 seen/flip bitmap words (32 KB)
#define WPC       256                // words per chunk
#define NCHUNKS   (NWORDS / WPC)     // 2048

// Seed: ONE blind atomicMin pass over a raster-prefix. Measured ceiling:
// scattered dword atomics ~25 G/s (32 B write-through each), independent of
// parallelism -> cost = count * 40ns. S=640K sits at the marginal-cost
// optimum vs flat-pass fallback (unseen labels = 256K*e^-2.5 ~ 21K).
#define SEED_TPB    256
#define SEED_BLOCKS 640
#define SEED_INT4   (SEED_BLOCKS * SEED_TPB)     // 163,840 int4 = 655,360 sites
#define SEED_SITES  (SEED_INT4 * 4)
#define ZERO_BLOCKS 512                          // zero the 2 MB bitmap
#define PRE_BLOCKS  512                          // stream labels to warm L2/L3

// Flat passes: persistent geometry. 512 blocks x 1024 thr = 2 resident
// blocks/CU (32 KB LDS -> 64 KB slot), 32 waves/CU; LDS staged once.
#define FLAT_BLOCKS 512
#define FLAT_TPB    1024
#define FLAT_THREADS (FLAT_BLOCKS * FLAT_TPB)   // 524,288; n4 = 8 * this

// plain ext-vector type for nontemporal builtins (HIP_vector_type is rejected)
typedef float f32x4 __attribute__((ext_vector_type(4)));

// ---------------- kernel 1: init first_idx + lookback state ----------------
__global__ void k_init(int* __restrict__ first_idx, unsigned long long* __restrict__ state) {
    int t = blockIdx.x * blockDim.x + threadIdx.x;   // N_LABELS threads
    first_idx[t] = INT_MAX;
    if (t < NCHUNKS) state[t] = 0ull;
}

// ---------------- kernel 2a: blind seed + bitmap zero + label prefetch ----------------
// Seed blocks: blind atomicMin over the prefix (commutative -> exact min; a
// label present in the prefix has its global first occurrence there too).
// Zero blocks: clear the 2 MB occupancy bitmap for k_scatter.
// Prefetch blocks: stream ALL labels with normal loads to allocate them in
// L2/L3 while the seed is atomic-pipe-bound (~830 GB/s of 6.3 TB/s used) --
// k_first_flat's label reads then hit cache.
__global__ void k_seed_blind(const int4* __restrict__ lab4, int* __restrict__ first_idx,
                             uint4* __restrict__ bitmap4, int* __restrict__ sink) {
    if (blockIdx.x < SEED_BLOCKS) {
        int t = blockIdx.x * blockDim.x + threadIdx.x;   // [0, SEED_INT4)
        int4 L = lab4[t];
        int b  = t * 4;
        atomicMin(&first_idx[L.x], b);
        atomicMin(&first_idx[L.y], b + 1);
        atomicMin(&first_idx[L.z], b + 2);
        atomicMin(&first_idx[L.w], b + 3);
    } else if (blockIdx.x < SEED_BLOCKS + ZERO_BLOCKS) {
        int i = (blockIdx.x - SEED_BLOCKS) * blockDim.x + threadIdx.x;
        bitmap4[i] = make_uint4(0u, 0u, 0u, 0u);   // 131,072 uint4
    } else {
        int i = (blockIdx.x - SEED_BLOCKS - ZERO_BLOCKS) * blockDim.x + threadIdx.x;
        const int stride = PRE_BLOCKS * SEED_TPB;        // 131,072
        int acc = 0;
        for (int t = i; t < N_SITES / 4; t += stride) {  // 32 iterations
            int4 v = lab4[t];
            acc ^= v.x ^ v.y ^ v.z ^ v.w;
        }
        if (acc == 0x7FFFFFFF) sink[0] = acc;            // keep loads alive
    }
}

// ---------------- kernel 2b: build 32 KB 'seen' bitmap from first_idx ----------------
__global__ void k_seen(const int* __restrict__ first_idx, unsigned* __restrict__ seen) {
    int l = blockIdx.x * blockDim.x + threadIdx.x;       // N_LABELS threads
    unsigned long long m = __ballot(first_idx[l] != INT_MAX);
    int lane = threadIdx.x & 63;
    if (lane == 0)       seen[l >> 5] = (unsigned)m;
    else if (lane == 32) seen[l >> 5] = (unsigned)(m >> 32);
}

// ---------------- kernel 2c: completion pass over ALL sites (persistent) ----------------
// 32 KB read-only 'seen' bitmap staged in LDS once per block. A set bit
// implies first_idx[l] already holds the exact global first index, so
// skipping is exact. Clear bits (~8% of labels) take the filtered-atomic path.
__global__ void __launch_bounds__(FLAT_TPB)
k_first_flat(const int4* __restrict__ lab4, int* __restrict__ first_idx,
             const unsigned* __restrict__ seen) {
    __shared__ unsigned slds[NSEENW];
    {
        const uint4* s4 = (const uint4*)seen;
        uint4*       d4 = (uint4*)slds;
        for (int i = threadIdx.x; i < NSEENW / 4; i += blockDim.x) d4[i] = s4[i];
    }
    __syncthreads();
    int base = blockIdx.x * blockDim.x + threadIdx.x;
#define PROBE(lbl, idx)                                                        \
    if (!((slds[(lbl) >> 5] >> ((lbl) & 31)) & 1u)) {                          \
        if ((idx) < first_idx[(lbl)]) atomicMin(&first_idx[(lbl)], (idx));     \
    }
    #pragma unroll
    for (int it = 0; it < 2; ++it) {
        int t0 = base + it * 4 * FLAT_THREADS;
        int4 L0 = lab4[t0];
        int4 L1 = lab4[t0 + FLAT_THREADS];
        int4 L2 = lab4[t0 + 2 * FLAT_THREADS];
        int4 L3 = lab4[t0 + 3 * FLAT_THREADS];
        int b0 = t0 * 4, b1 = (t0 + FLAT_THREADS) * 4;
        int b2 = (t0 + 2 * FLAT_THREADS) * 4, b3 = (t0 + 3 * FLAT_THREADS) * 4;
        PROBE(L0.x, b0)     PROBE(L0.y, b0 + 1) PROBE(L0.z, b0 + 2) PROBE(L0.w, b0 + 3)
        PROBE(L1.x, b1)     PROBE(L1.y, b1 + 1) PROBE(L1.z, b1 + 2) PROBE(L1.w, b1 + 3)
        PROBE(L2.x, b2)     PROBE(L2.y, b2 + 1) PROBE(L2.z, b2 + 2) PROBE(L2.w, b2 + 3)
        PROBE(L3.x, b3)     PROBE(L3.y, b3 + 1) PROBE(L3.z, b3 + 2) PROBE(L3.w, b3 + 3)
    }
#undef PROBE
}

// ---------------- kernel 3: scatter seed bits into occupancy bitmap ----------------
__global__ void k_scatter(const int* __restrict__ first_idx, unsigned* __restrict__ bitmap) {
    int l = blockIdx.x * blockDim.x + threadIdx.x;
    if (l >= N_LABELS) return;
    int fi = first_idx[l];
    if (fi != INT_MAX) atomicOr(&bitmap[fi >> 5], 1u << (fi & 31));
}

// ---------------- kernel 4: fused popcount + decoupled-lookback scan ----------------
// One block per 256-word chunk (2048 blocks x 256 thr; VGPR/LDS tiny -> all
// 2048 blocks co-resident at 8 blocks/CU, so the lookback spin cannot
// deadlock). state[b] packs {flag(1=agg,2=incl) << 32 | value}. Result is
// exact integer arithmetic -> deterministic regardless of timing.
__global__ void k_scan_fused(const unsigned* __restrict__ bitmap,
                             int* __restrict__ wordPrefix,
                             unsigned long long* __restrict__ state) {
    __shared__ int wsum[4];
    __shared__ int sbase;
    int tid = threadIdx.x, lane = tid & 63, wid = tid >> 6;
    int w  = blockIdx.x * WPC + tid;
    int pc = __popc(bitmap[w]);
    int v = pc;
    #pragma unroll
    for (int off = 1; off < 64; off <<= 1) {
        int u = __shfl_up(v, off);
        if (lane >= off) v += u;
    }
    if (lane == 63) wsum[wid] = v;
    __syncthreads();
    int waveoff = 0;
    #pragma unroll
    for (int i = 0; i < 4; ++i) waveoff += (i < wid) ? wsum[i] : 0;
    int total = wsum[0] + wsum[1] + wsum[2] + wsum[3];
    if (tid == 0) {
        int b = blockIdx.x;
        int base = 0;
        if (b == 0) {
            __hip_atomic_store(&state[0], (2ull << 32) | (unsigned)total,
                               __ATOMIC_RELEASE, __HIP_MEMORY_SCOPE_AGENT);
        } else {
            __hip_atomic_store(&state[b], (1ull << 32) | (unsigned)total,
                               __ATOMIC_RELEASE, __HIP_MEMORY_SCOPE_AGENT);
            for (int j = b - 1; j >= 0; ) {
                unsigned long long s;
                do {
                    s = __hip_atomic_load(&state[j], __ATOMIC_ACQUIRE,
                                          __HIP_MEMORY_SCOPE_AGENT);
                } while ((s >> 32) == 0ull);
                base += (int)(unsigned)s;
                if ((s >> 32) == 2ull) break;
                --j;
            }
            __hip_atomic_store(&state[b], (2ull << 32) | (unsigned)(base + total),
                               __ATOMIC_RELEASE, __HIP_MEMORY_SCOPE_AGENT);
        }
        sbase = base;
    }
    __syncthreads();
    wordPrefix[w] = sbase + waveoff + v - pc;   // global exclusive prefix
}

// ---------------- kernel 5: rank -> coin -> flip bit (ballot, NO atomics) ----------------
__global__ void k_rank_flip(const int* __restrict__ first_idx,
                            const unsigned* __restrict__ bitmap,
                            const int* __restrict__ wordPrefix,
                            const float* __restrict__ coins,
                            unsigned* __restrict__ flipbits) {
    int l = blockIdx.x * blockDim.x + threadIdx.x;   // N_LABELS threads
    int fi = first_idx[l];
    bool flip = false;
    if (fi != INT_MAX) {
        int w = fi >> 5;
        unsigned mask = (1u << (fi & 31)) - 1u;
        int rank = wordPrefix[w] + __popc(bitmap[w] & mask);
        flip = (coins[rank] >= 0.5f);
    }
    unsigned long long m = __ballot(flip);
    int lane = threadIdx.x & 63;
    if (lane == 0)       flipbits[l >> 5] = (unsigned)m;
    else if (lane == 32) flipbits[l >> 5] = (unsigned)(m >> 32);
}

// ---------------- kernel 6: apply flips (persistent, LDS table, nt streams) ----------------
__global__ void __launch_bounds__(FLAT_TPB)
k_out(const int4* __restrict__ lab4, const float* __restrict__ spins,
      const unsigned* __restrict__ flipbits, float* __restrict__ out) {
    __shared__ unsigned flds[NSEENW];
    {
        const uint4* s4 = (const uint4*)flipbits;
        uint4*       d4 = (uint4*)flds;
        for (int i = threadIdx.x; i < NSEENW / 4; i += blockDim.x) d4[i] = s4[i];
    }
    __syncthreads();
    const f32x4* sp4  = (const f32x4*)spins;
    f32x4*       out4 = (f32x4*)out;
    int base = blockIdx.x * blockDim.x + threadIdx.x;
#define FLIP1(lbl, sv) __uint_as_float(__float_as_uint(sv) ^                   \
        ((((flds[(lbl) >> 5] >> ((lbl) & 31)) & 1u)) << 31))
    #pragma unroll
    for (int it = 0; it < 2; ++it) {
        int t0 = base + it * 4 * FLAT_THREADS;
        int4  L0 = lab4[t0];
        int4  L1 = lab4[t0 + FLAT_THREADS];
        int4  L2 = lab4[t0 + 2 * FLAT_THREADS];
        int4  L3 = lab4[t0 + 3 * FLAT_THREADS];
        f32x4 s0 = __builtin_nontemporal_load(&sp4[t0]);
        f32x4 s1 = __builtin_nontemporal_load(&sp4[t0 + FLAT_THREADS]);
        f32x4 s2 = __builtin_nontemporal_load(&sp4[t0 + 2 * FLAT_THREADS]);
        f32x4 s3 = __builtin_nontemporal_load(&sp4[t0 + 3 * FLAT_THREADS]);
        f32x4 o0, o1, o2, o3;
        o0.x = FLIP1(L0.x, s0.x); o0.y = FLIP1(L0.y, s0.y);
        o0.z = FLIP1(L0.z, s0.z); o0.w = FLIP1(L0.w, s0.w);
        o1.x = FLIP1(L1.x, s1.x); o1.y = FLIP1(L1.y, s1.y);
        o1.z = FLIP1(L1.z, s1.z); o1.w = FLIP1(L1.w, s1.w);
        o2.x = FLIP1(L2.x, s2.x); o2.y = FLIP1(L2.y, s2.y);
        o2.z = FLIP1(L2.z, s2.z); o2.w = FLIP1(L2.w, s2.w);
        o3.x = FLIP1(L3.x, s3.x); o3.y = FLIP1(L3.y, s3.y);
        o3.z = FLIP1(L3.z, s3.z); o3.w = FLIP1(L3.w, s3.w);
        __builtin_nontemporal_store(o0, &out4[t0]);
        __builtin_nontemporal_store(o1, &out4[t0 + FLAT_THREADS]);
        __builtin_nontemporal_store(o2, &out4[t0 + 2 * FLAT_THREADS]);
        __builtin_nontemporal_store(o3, &out4[t0 + 3 * FLAT_THREADS]);
    }
#undef FLIP1
}

extern "C" void kernel_launch(void* const* d_in, const int* in_sizes, int n_in,
                              void* d_out, int out_size, void* d_ws, size_t ws_size,
                              hipStream_t stream) {
    const float* spins  = (const float*)d_in[0];
    const int*   labels = (const int*)d_in[1];
    const float* coins  = (const float*)d_in[2];
    float*       out    = (float*)d_out;

    // workspace layout (~5.2 MB total)
    char* ws = (char*)d_ws;
    int*                first_idx  = (int*)ws;                              // 1 MB
    unsigned*           bitmap     = (unsigned*)(ws + (1u << 20));          // 2 MB
    int*                wordPrefix = (int*)(ws + 3u * (1u << 20));          // 2 MB
    unsigned long long* state      = (unsigned long long*)(ws + 5u * (1u << 20)); // 16 KB
    unsigned*           seen       = (unsigned*)(ws + 5u*(1u<<20) + (1u<<15));    // 32 KB
    unsigned*           flipbits   = (unsigned*)(ws + 5u*(1u<<20) + 2u*(1u<<15)); // 32 KB
    int*                sink       = (int*)(ws + 5u*(1u<<20) + 3u*(1u<<15));      // 4 B

    k_init<<<N_LABELS / 256, 256, 0, stream>>>(first_idx, state);
    k_seed_blind<<<SEED_BLOCKS + ZERO_BLOCKS + PRE_BLOCKS, SEED_TPB, 0, stream>>>(
        (const int4*)labels, first_idx, (uint4*)bitmap, sink);
    k_seen<<<N_LABELS / 256, 256, 0, stream>>>(first_idx, seen);
    k_first_flat<<<FLAT_BLOCKS, FLAT_TPB, 0, stream>>>((const int4*)labels, first_idx, seen);
    k_scatter<<<N_LABELS / 256, 256, 0, stream>>>(first_idx, bitmap);
    k_scan_fused<<<NCHUNKS, WPC, 0, stream>>>(bitmap, wordPrefix, state);
    k_rank_flip<<<N_LABELS / 256, 256, 0, stream>>>(first_idx, bitmap, wordPrefix, coins, flipbits);
    k_out<<<FLAT_BLOCKS, FLAT_TPB, 0, stream>>>((const int4*)labels, (const float*)spins,
                                                flipbits, (float*)out);
}

// Round 14
// 133.294 us; speedup vs baseline: 8.5814x; 8.5814x over previous
//
#include <hip/hip_runtime.h>
#include <limits.h>

// Problem constants (fixed by the reference: LATTICE=(4096,4096), N_CLUSTERS=262144)
#define N_SITES   (4096 * 4096)      // 16,777,216
#define N_LABELS  262144
#define NWORDS    (N_SITES / 32)     // 524,288 bitmap words
#define NSEENW    (N_LABELS / 32)    // 8,192 seen/flip bitmap words (32 KB)
#define WPC       256                // words per chunk
#define NCHUNKS   (NWORDS / WPC)     // 2048

// Seed: ONE blind atomicMin pass over a raster-prefix. Measured ceiling:
// scattered dword atomics ~25 G/s (32 B write-through each), independent of
// parallelism -> cost = count * 40ns. S=640K sits at the marginal-cost
// optimum vs flat-pass fallback (unseen labels = 256K*e^-2.5 ~ 21K).
#define SEED_TPB    256
#define SEED_BLOCKS 640
#define SEED_INT4   (SEED_BLOCKS * SEED_TPB)     // 163,840 int4 = 655,360 sites
#define SEED_SITES  (SEED_INT4 * 4)
#define ZERO_BLOCKS 512                          // zero the 2 MB bitmap
#define PRE_BLOCKS  512                          // stream labels to warm L2/L3

// Flat passes: persistent geometry. 512 blocks x 1024 thr = 2 resident
// blocks/CU (32 KB LDS -> 64 KB slot), 32 waves/CU; LDS staged once.
#define FLAT_BLOCKS 512
#define FLAT_TPB    1024
#define FLAT_THREADS (FLAT_BLOCKS * FLAT_TPB)   // 524,288; n4 = 8 * this

// plain ext-vector type for nontemporal builtins (HIP_vector_type is rejected)
typedef float f32x4 __attribute__((ext_vector_type(4)));

// ---------------- kernel 1: init first_idx ----------------
__global__ void k_init(int* __restrict__ first_idx) {
    int t = blockIdx.x * blockDim.x + threadIdx.x;   // N_LABELS threads
    first_idx[t] = INT_MAX;
}

// ---------------- kernel 2a: blind seed + bitmap zero + label prefetch ----------------
// Seed blocks: blind atomicMin over the prefix (commutative -> exact min; a
// label present in the prefix has its global first occurrence there too).
// Zero blocks: clear the 2 MB occupancy bitmap for k_scatter.
// Prefetch blocks: stream ALL labels with normal loads to allocate them in
// L2/L3 while the seed is atomic-pipe-bound -- k_first_flat then hits cache.
__global__ void k_seed_blind(const int4* __restrict__ lab4, int* __restrict__ first_idx,
                             uint4* __restrict__ bitmap4, int* __restrict__ sink) {
    if (blockIdx.x < SEED_BLOCKS) {
        int t = blockIdx.x * blockDim.x + threadIdx.x;   // [0, SEED_INT4)
        int4 L = lab4[t];
        int b  = t * 4;
        atomicMin(&first_idx[L.x], b);
        atomicMin(&first_idx[L.y], b + 1);
        atomicMin(&first_idx[L.z], b + 2);
        atomicMin(&first_idx[L.w], b + 3);
    } else if (blockIdx.x < SEED_BLOCKS + ZERO_BLOCKS) {
        int i = (blockIdx.x - SEED_BLOCKS) * blockDim.x + threadIdx.x;
        bitmap4[i] = make_uint4(0u, 0u, 0u, 0u);   // 131,072 uint4
    } else {
        int i = (blockIdx.x - SEED_BLOCKS - ZERO_BLOCKS) * blockDim.x + threadIdx.x;
        const int stride = PRE_BLOCKS * SEED_TPB;        // 131,072
        int acc = 0;
        for (int t = i; t < N_SITES / 4; t += stride) {  // 32 iterations
            int4 v = lab4[t];
            acc ^= v.x ^ v.y ^ v.z ^ v.w;
        }
        if (acc == 0x7FFFFFFF) sink[0] = acc;            // keep loads alive
    }
}

// ---------------- kernel 2b: build 32 KB 'seen' bitmap from first_idx ----------------
__global__ void k_seen(const int* __restrict__ first_idx, unsigned* __restrict__ seen) {
    int l = blockIdx.x * blockDim.x + threadIdx.x;       // N_LABELS threads
    unsigned long long m = __ballot(first_idx[l] != INT_MAX);
    int lane = threadIdx.x & 63;
    if (lane == 0)       seen[l >> 5] = (unsigned)m;
    else if (lane == 32) seen[l >> 5] = (unsigned)(m >> 32);
}

// ---------------- kernel 2c: completion pass over ALL sites (persistent) ----------------
// 32 KB read-only 'seen' bitmap staged in LDS once per block. A set bit
// implies first_idx[l] already holds the exact global first index, so
// skipping is exact. Clear bits (~8% of labels) take the filtered-atomic path.
__global__ void __launch_bounds__(FLAT_TPB)
k_first_flat(const int4* __restrict__ lab4, int* __restrict__ first_idx,
             const unsigned* __restrict__ seen) {
    __shared__ unsigned slds[NSEENW];
    {
        const uint4* s4 = (const uint4*)seen;
        uint4*       d4 = (uint4*)slds;
        for (int i = threadIdx.x; i < NSEENW / 4; i += blockDim.x) d4[i] = s4[i];
    }
    __syncthreads();
    int base = blockIdx.x * blockDim.x + threadIdx.x;
#define PROBE(lbl, idx)                                                        \
    if (!((slds[(lbl) >> 5] >> ((lbl) & 31)) & 1u)) {                          \
        if ((idx) < first_idx[(lbl)]) atomicMin(&first_idx[(lbl)], (idx));     \
    }
    #pragma unroll
    for (int it = 0; it < 2; ++it) {
        int t0 = base + it * 4 * FLAT_THREADS;
        int4 L0 = lab4[t0];
        int4 L1 = lab4[t0 + FLAT_THREADS];
        int4 L2 = lab4[t0 + 2 * FLAT_THREADS];
        int4 L3 = lab4[t0 + 3 * FLAT_THREADS];
        int b0 = t0 * 4, b1 = (t0 + FLAT_THREADS) * 4;
        int b2 = (t0 + 2 * FLAT_THREADS) * 4, b3 = (t0 + 3 * FLAT_THREADS) * 4;
        PROBE(L0.x, b0)     PROBE(L0.y, b0 + 1) PROBE(L0.z, b0 + 2) PROBE(L0.w, b0 + 3)
        PROBE(L1.x, b1)     PROBE(L1.y, b1 + 1) PROBE(L1.z, b1 + 2) PROBE(L1.w, b1 + 3)
        PROBE(L2.x, b2)     PROBE(L2.y, b2 + 1) PROBE(L2.z, b2 + 2) PROBE(L2.w, b2 + 3)
        PROBE(L3.x, b3)     PROBE(L3.y, b3 + 1) PROBE(L3.z, b3 + 2) PROBE(L3.w, b3 + 3)
    }
#undef PROBE
}

// ---------------- kernel 3: scatter seed bits into occupancy bitmap ----------------
__global__ void k_scatter(const int* __restrict__ first_idx, unsigned* __restrict__ bitmap) {
    int l = blockIdx.x * blockDim.x + threadIdx.x;
    if (l >= N_LABELS) return;
    int fi = first_idx[l];
    if (fi != INT_MAX) atomicOr(&bitmap[fi >> 5], 1u << (fi & 31));
}

// ---------------- kernel 4: per-chunk popcount sums ----------------
__global__ void k_chunk_sums(const unsigned* __restrict__ bitmap, int* __restrict__ chunkSums) {
    __shared__ int waveSums[4];
    int w  = blockIdx.x * WPC + threadIdx.x;
    int pc = __popc(bitmap[w]);
    #pragma unroll
    for (int off = 32; off; off >>= 1) pc += __shfl_down(pc, off);
    if ((threadIdx.x & 63) == 0) waveSums[threadIdx.x >> 6] = pc;
    __syncthreads();
    if (threadIdx.x == 0)
        chunkSums[blockIdx.x] = waveSums[0] + waveSums[1] + waveSums[2] + waveSums[3];
}

// ---------------- kernel 5: exclusive scan of 2048 chunk sums (1 block, shfl) ----------------
__global__ void k_scan(int* __restrict__ data, int n) {   // n = 2048, 1024 threads
    __shared__ int wsum[16];
    int tid = threadIdx.x, lane = tid & 63, wid = tid >> 6;
    int carry = 0;
    for (int base = 0; base < n; base += 1024) {
        int orig = data[base + tid];
        int v = orig;
        #pragma unroll
        for (int off = 1; off < 64; off <<= 1) {
            int u = __shfl_up(v, off);
            if (lane >= off) v += u;
        }
        if (lane == 63) wsum[wid] = v;
        __syncthreads();
        if (tid < 16) {
            int w = wsum[tid];
            #pragma unroll
            for (int off = 1; off < 16; off <<= 1) {
                int u = __shfl_up(w, off);
                if (tid >= off) w += u;
            }
            wsum[tid] = w;
        }
        __syncthreads();
        int incl  = v + (wid ? wsum[wid - 1] : 0);
        int total = wsum[15];
        __syncthreads();                   // protect wsum before next tile
        data[base + tid] = incl - orig + carry;   // exclusive prefix
        carry += total;
    }
}

// ---------------- kernel 6: per-word global exclusive prefix (shfl) ----------------
__global__ void k_word_prefix(const unsigned* __restrict__ bitmap,
                              const int* __restrict__ chunkPref,
                              int* __restrict__ wordPrefix) {
    __shared__ int wsum[4];
    int tid = threadIdx.x, lane = tid & 63, wid = tid >> 6;
    int w   = blockIdx.x * WPC + tid;
    int pc  = __popc(bitmap[w]);
    int v = pc;
    #pragma unroll
    for (int off = 1; off < 64; off <<= 1) {
        int u = __shfl_up(v, off);
        if (lane >= off) v += u;
    }
    if (lane == 63) wsum[wid] = v;
    __syncthreads();
    int waveoff = 0;
    #pragma unroll
    for (int i = 0; i < 4; ++i) waveoff += (i < wid) ? wsum[i] : 0;
    wordPrefix[w] = chunkPref[blockIdx.x] + waveoff + v - pc;  // exclusive
}

// ---------------- kernel 7: rank -> coin -> flip bit (ballot, NO atomics) ----------------
__global__ void k_rank_flip(const int* __restrict__ first_idx,
                            const unsigned* __restrict__ bitmap,
                            const int* __restrict__ wordPrefix,
                            const float* __restrict__ coins,
                            unsigned* __restrict__ flipbits) {
    int l = blockIdx.x * blockDim.x + threadIdx.x;   // N_LABELS threads
    int fi = first_idx[l];
    bool flip = false;
    if (fi != INT_MAX) {
        int w = fi >> 5;
        unsigned mask = (1u << (fi & 31)) - 1u;
        int rank = wordPrefix[w] + __popc(bitmap[w] & mask);
        flip = (coins[rank] >= 0.5f);
    }
    unsigned long long m = __ballot(flip);
    int lane = threadIdx.x & 63;
    if (lane == 0)       flipbits[l >> 5] = (unsigned)m;
    else if (lane == 32) flipbits[l >> 5] = (unsigned)(m >> 32);
}

// ---------------- kernel 8: apply flips (persistent, LDS table, nt streams) ----------------
__global__ void __launch_bounds__(FLAT_TPB)
k_out(const int4* __restrict__ lab4, const float* __restrict__ spins,
      const unsigned* __restrict__ flipbits, float* __restrict__ out) {
    __shared__ unsigned flds[NSEENW];
    {
        const uint4* s4 = (const uint4*)flipbits;
        uint4*       d4 = (uint4*)flds;
        for (int i = threadIdx.x; i < NSEENW / 4; i += blockDim.x) d4[i] = s4[i];
    }
    __syncthreads();
    const f32x4* sp4  = (const f32x4*)spins;
    f32x4*       out4 = (f32x4*)out;
    int base = blockIdx.x * blockDim.x + threadIdx.x;
#define FLIP1(lbl, sv) __uint_as_float(__float_as_uint(sv) ^                   \
        ((((flds[(lbl) >> 5] >> ((lbl) & 31)) & 1u)) << 31))
    #pragma unroll
    for (int it = 0; it < 2; ++it) {
        int t0 = base + it * 4 * FLAT_THREADS;
        int4  L0 = lab4[t0];
        int4  L1 = lab4[t0 + FLAT_THREADS];
        int4  L2 = lab4[t0 + 2 * FLAT_THREADS];
        int4  L3 = lab4[t0 + 3 * FLAT_THREADS];
        f32x4 s0 = __builtin_nontemporal_load(&sp4[t0]);
        f32x4 s1 = __builtin_nontemporal_load(&sp4[t0 + FLAT_THREADS]);
        f32x4 s2 = __builtin_nontemporal_load(&sp4[t0 + 2 * FLAT_THREADS]);
        f32x4 s3 = __builtin_nontemporal_load(&sp4[t0 + 3 * FLAT_THREADS]);
        f32x4 o0, o1, o2, o3;
        o0.x = FLIP1(L0.x, s0.x); o0.y = FLIP1(L0.y, s0.y);
        o0.z = FLIP1(L0.z, s0.z); o0.w = FLIP1(L0.w, s0.w);
        o1.x = FLIP1(L1.x, s1.x); o1.y = FLIP1(L1.y, s1.y);
        o1.z = FLIP1(L1.z, s1.z); o1.w = FLIP1(L1.w, s1.w);
        o2.x = FLIP1(L2.x, s2.x); o2.y = FLIP1(L2.y, s2.y);
        o2.z = FLIP1(L2.z, s2.z); o2.w = FLIP1(L2.w, s2.w);
        o3.x = FLIP1(L3.x, s3.x); o3.y = FLIP1(L3.y, s3.y);
        o3.z = FLIP1(L3.z, s3.z); o3.w = FLIP1(L3.w, s3.w);
        __builtin_nontemporal_store(o0, &out4[t0]);
        __builtin_nontemporal_store(o1, &out4[t0 + FLAT_THREADS]);
        __builtin_nontemporal_store(o2, &out4[t0 + 2 * FLAT_THREADS]);
        __builtin_nontemporal_store(o3, &out4[t0 + 3 * FLAT_THREADS]);
    }
#undef FLIP1
}

extern "C" void kernel_launch(void* const* d_in, const int* in_sizes, int n_in,
                              void* d_out, int out_size, void* d_ws, size_t ws_size,
                              hipStream_t stream) {
    const float* spins  = (const float*)d_in[0];
    const int*   labels = (const int*)d_in[1];
    const float* coins  = (const float*)d_in[2];
    float*       out    = (float*)d_out;

    // workspace layout (~5.2 MB total)
    char* ws = (char*)d_ws;
    int*      first_idx  = (int*)ws;                                   // 1 MB
    unsigned* bitmap     = (unsigned*)(ws + (1u << 20));               // 2 MB
    int*      wordPrefix = (int*)(ws + 3u * (1u << 20));               // 2 MB
    int*      chunkSums  = (int*)(ws + 5u * (1u << 20));               // 8 KB
    unsigned* seen       = (unsigned*)(ws + 5u*(1u<<20) + (1u<<15));   // 32 KB
    unsigned* flipbits   = (unsigned*)(ws + 5u*(1u<<20) + 2u*(1u<<15)); // 32 KB
    int*      sink       = (int*)(ws + 5u*(1u<<20) + 3u*(1u<<15));      // 4 B

    k_init<<<N_LABELS / 256, 256, 0, stream>>>(first_idx);
    k_seed_blind<<<SEED_BLOCKS + ZERO_BLOCKS + PRE_BLOCKS, SEED_TPB, 0, stream>>>(
        (const int4*)labels, first_idx, (uint4*)bitmap, sink);
    k_seen<<<N_LABELS / 256, 256, 0, stream>>>(first_idx, seen);
    k_first_flat<<<FLAT_BLOCKS, FLAT_TPB, 0, stream>>>((const int4*)labels, first_idx, seen);
    k_scatter<<<N_LABELS / 256, 256, 0, stream>>>(first_idx, bitmap);
    k_chunk_sums<<<NCHUNKS, WPC, 0, stream>>>(bitmap, chunkSums);
    k_scan<<<1, 1024, 0, stream>>>(chunkSums, NCHUNKS);
    k_word_prefix<<<NCHUNKS, WPC, 0, stream>>>(bitmap, chunkSums, wordPrefix);
    k_rank_flip<<<N_LABELS / 256, 256, 0, stream>>>(first_idx, bitmap, wordPrefix, coins, flipbits);
    k_out<<<FLAT_BLOCKS, FLAT_TPB, 0, stream>>>((const int4*)labels, (const float*)spins,
                                                flipbits, (float*)out);
}

// Round 15
// 125.232 us; speedup vs baseline: 9.1339x; 1.0644x over previous
//
#include <hip/hip_runtime.h>
#include <limits.h>

// Problem constants (fixed by the reference: LATTICE=(4096,4096), N_CLUSTERS=262144)
#define N_SITES   (4096 * 4096)      // 16,777,216
#define N_LABELS  262144
#define NWORDS    (N_SITES / 32)     // 524,288 bitmap words
#define NSEENW    (N_LABELS / 32)    // 8,192 seen/flip bitmap words (32 KB)
#define WPC       256                // words per chunk
#define NCHUNKS   (NWORDS / WPC)     // 2048

// Seed: ONE blind atomicMin pass over a raster-prefix. Measured ceiling:
// scattered dword atomics ~25 G/s (32 B write-through each), independent of
// parallelism -> cost = count * 40ns. S=640K ~ marginal-cost optimum.
// (R14 lesson: co-launched label prefetch is a latency-chain tail that
// stretches this dispatch ~+17us with no flat-pass gain -- labels are
// already L3-resident. Removed.)
#define SEED_TPB    256
#define SEED_BLOCKS 640
#define SEED_INT4   (SEED_BLOCKS * SEED_TPB)     // 163,840 int4 = 655,360 sites
#define ZERO_BLOCKS 512                          // zero the 2 MB bitmap

// Flat passes: persistent geometry. 512 blocks x 1024 thr = 2 resident
// blocks/CU (32 KB LDS -> 64 KB slot), 32 waves/CU; LDS staged once.
#define FLAT_BLOCKS 512
#define FLAT_TPB    1024
#define FLAT_THREADS (FLAT_BLOCKS * FLAT_TPB)   // 524,288; n4 = 8 * this

// plain ext-vector type for nontemporal builtins (HIP_vector_type is rejected)
typedef float f32x4 __attribute__((ext_vector_type(4)));

// ---------------- kernel 1: init first_idx ----------------
__global__ void k_init(int* __restrict__ first_idx) {
    int t = blockIdx.x * blockDim.x + threadIdx.x;   // N_LABELS threads
    first_idx[t] = INT_MAX;
}

// ---------------- kernel 2a: blind seed + bitmap zero ----------------
// Seed blocks: blind atomicMin over the prefix (commutative -> exact min; a
// label present in the prefix has its global first occurrence there too).
// Zero blocks: clear the 2 MB occupancy bitmap for k_scatter.
__global__ void k_seed_blind(const int4* __restrict__ lab4, int* __restrict__ first_idx,
                             uint4* __restrict__ bitmap4) {
    if (blockIdx.x < SEED_BLOCKS) {
        int t = blockIdx.x * blockDim.x + threadIdx.x;   // [0, SEED_INT4)
        int4 L = lab4[t];
        int b  = t * 4;
        atomicMin(&first_idx[L.x], b);
        atomicMin(&first_idx[L.y], b + 1);
        atomicMin(&first_idx[L.z], b + 2);
        atomicMin(&first_idx[L.w], b + 3);
    } else {
        int i = (blockIdx.x - SEED_BLOCKS) * blockDim.x + threadIdx.x;
        bitmap4[i] = make_uint4(0u, 0u, 0u, 0u);   // 131,072 uint4
    }
}

// ---------------- kernel 2b: build 32 KB 'seen' bitmap from first_idx ----------------
__global__ void k_seen(const int* __restrict__ first_idx, unsigned* __restrict__ seen) {
    int l = blockIdx.x * blockDim.x + threadIdx.x;       // N_LABELS threads
    unsigned long long m = __ballot(first_idx[l] != INT_MAX);
    int lane = threadIdx.x & 63;
    if (lane == 0)       seen[l >> 5] = (unsigned)m;
    else if (lane == 32) seen[l >> 5] = (unsigned)(m >> 32);
}

// ---------------- kernel 2c: completion pass over ALL sites (persistent) ----------------
// 32 KB read-only 'seen' bitmap staged in LDS once per block. A set bit
// implies first_idx[l] already holds the exact global first index, so
// skipping is exact. Clear bits (~8% of labels) take the filtered-atomic path.
__global__ void __launch_bounds__(FLAT_TPB)
k_first_flat(const int4* __restrict__ lab4, int* __restrict__ first_idx,
             const unsigned* __restrict__ seen) {
    __shared__ unsigned slds[NSEENW];
    {
        const uint4* s4 = (const uint4*)seen;
        uint4*       d4 = (uint4*)slds;
        for (int i = threadIdx.x; i < NSEENW / 4; i += blockDim.x) d4[i] = s4[i];
    }
    __syncthreads();
    int base = blockIdx.x * blockDim.x + threadIdx.x;
#define PROBE(lbl, idx)                                                        \
    if (!((slds[(lbl) >> 5] >> ((lbl) & 31)) & 1u)) {                          \
        if ((idx) < first_idx[(lbl)]) atomicMin(&first_idx[(lbl)], (idx));     \
    }
    #pragma unroll
    for (int it = 0; it < 2; ++it) {
        int t0 = base + it * 4 * FLAT_THREADS;
        int4 L0 = lab4[t0];
        int4 L1 = lab4[t0 + FLAT_THREADS];
        int4 L2 = lab4[t0 + 2 * FLAT_THREADS];
        int4 L3 = lab4[t0 + 3 * FLAT_THREADS];
        int b0 = t0 * 4, b1 = (t0 + FLAT_THREADS) * 4;
        int b2 = (t0 + 2 * FLAT_THREADS) * 4, b3 = (t0 + 3 * FLAT_THREADS) * 4;
        PROBE(L0.x, b0)     PROBE(L0.y, b0 + 1) PROBE(L0.z, b0 + 2) PROBE(L0.w, b0 + 3)
        PROBE(L1.x, b1)     PROBE(L1.y, b1 + 1) PROBE(L1.z, b1 + 2) PROBE(L1.w, b1 + 3)
        PROBE(L2.x, b2)     PROBE(L2.y, b2 + 1) PROBE(L2.z, b2 + 2) PROBE(L2.w, b2 + 3)
        PROBE(L3.x, b3)     PROBE(L3.y, b3 + 1) PROBE(L3.z, b3 + 2) PROBE(L3.w, b3 + 3)
    }
#undef PROBE
}

// ---------------- kernel 3: scatter seed bits into occupancy bitmap ----------------
__global__ void k_scatter(const int* __restrict__ first_idx, unsigned* __restrict__ bitmap) {
    int l = blockIdx.x * blockDim.x + threadIdx.x;
    if (l >= N_LABELS) return;
    int fi = first_idx[l];
    if (fi != INT_MAX) atomicOr(&bitmap[fi >> 5], 1u << (fi & 31));
}

// ---------------- kernel 4: per-chunk popcount sums ----------------
__global__ void k_chunk_sums(const unsigned* __restrict__ bitmap, int* __restrict__ chunkSums) {
    __shared__ int waveSums[4];
    int w  = blockIdx.x * WPC + threadIdx.x;
    int pc = __popc(bitmap[w]);
    #pragma unroll
    for (int off = 32; off; off >>= 1) pc += __shfl_down(pc, off);
    if ((threadIdx.x & 63) == 0) waveSums[threadIdx.x >> 6] = pc;
    __syncthreads();
    if (threadIdx.x == 0)
        chunkSums[blockIdx.x] = waveSums[0] + waveSums[1] + waveSums[2] + waveSums[3];
}

// ---------------- kernel 5: fused chunk-prefix reduce + per-word prefix ----------------
// Block b reduces chunkSums[0..b) itself (<= 8 KB, L2-hit, <= 8 loads/thread)
// -- replaces the separate single-block k_scan launch.
__global__ void k_word_prefix(const unsigned* __restrict__ bitmap,
                              const int* __restrict__ chunkSums,
                              int* __restrict__ wordPrefix) {
    __shared__ int wsum[4];
    __shared__ int rsum[4];
    int tid = threadIdx.x, lane = tid & 63, wid = tid >> 6;
    int b = blockIdx.x;
    // chunk prefix: block-reduce chunkSums[0..b)
    int acc = 0;
    for (int i = tid; i < b; i += WPC) acc += chunkSums[i];
    #pragma unroll
    for (int off = 32; off; off >>= 1) acc += __shfl_down(acc, off);
    if (lane == 0) rsum[wid] = acc;
    // per-word popcount scan
    int w  = b * WPC + tid;
    int pc = __popc(bitmap[w]);
    int v = pc;
    #pragma unroll
    for (int off = 1; off < 64; off <<= 1) {
        int u = __shfl_up(v, off);
        if (lane >= off) v += u;
    }
    if (lane == 63) wsum[wid] = v;
    __syncthreads();
    int chunkPref = rsum[0] + rsum[1] + rsum[2] + rsum[3];
    int waveoff = 0;
    #pragma unroll
    for (int i = 0; i < 4; ++i) waveoff += (i < wid) ? wsum[i] : 0;
    wordPrefix[w] = chunkPref + waveoff + v - pc;  // global exclusive prefix
}

// ---------------- kernel 6: rank -> coin -> flip bit (ballot, NO atomics) ----------------
__global__ void k_rank_flip(const int* __restrict__ first_idx,
                            const unsigned* __restrict__ bitmap,
                            const int* __restrict__ wordPrefix,
                            const float* __restrict__ coins,
                            unsigned* __restrict__ flipbits) {
    int l = blockIdx.x * blockDim.x + threadIdx.x;   // N_LABELS threads
    int fi = first_idx[l];
    bool flip = false;
    if (fi != INT_MAX) {
        int w = fi >> 5;
        unsigned mask = (1u << (fi & 31)) - 1u;
        int rank = wordPrefix[w] + __popc(bitmap[w] & mask);
        flip = (coins[rank] >= 0.5f);
    }
    unsigned long long m = __ballot(flip);
    int lane = threadIdx.x & 63;
    if (lane == 0)       flipbits[l >> 5] = (unsigned)m;
    else if (lane == 32) flipbits[l >> 5] = (unsigned)(m >> 32);
}

// ---------------- kernel 7: apply flips (persistent, LDS table, nt streams) ----------------
__global__ void __launch_bounds__(FLAT_TPB)
k_out(const int4* __restrict__ lab4, const float* __restrict__ spins,
      const unsigned* __restrict__ flipbits, float* __restrict__ out) {
    __shared__ unsigned flds[NSEENW];
    {
        const uint4* s4 = (const uint4*)flipbits;
        uint4*       d4 = (uint4*)flds;
        for (int i = threadIdx.x; i < NSEENW / 4; i += blockDim.x) d4[i] = s4[i];
    }
    __syncthreads();
    const f32x4* sp4  = (const f32x4*)spins;
    f32x4*       out4 = (f32x4*)out;
    int base = blockIdx.x * blockDim.x + threadIdx.x;
#define FLIP1(lbl, sv) __uint_as_float(__float_as_uint(sv) ^                   \
        ((((flds[(lbl) >> 5] >> ((lbl) & 31)) & 1u)) << 31))
    #pragma unroll
    for (int it = 0; it < 2; ++it) {
        int t0 = base + it * 4 * FLAT_THREADS;
        int4  L0 = lab4[t0];
        int4  L1 = lab4[t0 + FLAT_THREADS];
        int4  L2 = lab4[t0 + 2 * FLAT_THREADS];
        int4  L3 = lab4[t0 + 3 * FLAT_THREADS];
        f32x4 s0 = __builtin_nontemporal_load(&sp4[t0]);
        f32x4 s1 = __builtin_nontemporal_load(&sp4[t0 + FLAT_THREADS]);
        f32x4 s2 = __builtin_nontemporal_load(&sp4[t0 + 2 * FLAT_THREADS]);
        f32x4 s3 = __builtin_nontemporal_load(&sp4[t0 + 3 * FLAT_THREADS]);
        f32x4 o0, o1, o2, o3;
        o0.x = FLIP1(L0.x, s0.x); o0.y = FLIP1(L0.y, s0.y);
        o0.z = FLIP1(L0.z, s0.z); o0.w = FLIP1(L0.w, s0.w);
        o1.x = FLIP1(L1.x, s1.x); o1.y = FLIP1(L1.y, s1.y);
        o1.z = FLIP1(L1.z, s1.z); o1.w = FLIP1(L1.w, s1.w);
        o2.x = FLIP1(L2.x, s2.x); o2.y = FLIP1(L2.y, s2.y);
        o2.z = FLIP1(L2.z, s2.z); o2.w = FLIP1(L2.w, s2.w);
        o3.x = FLIP1(L3.x, s3.x); o3.y = FLIP1(L3.y, s3.y);
        o3.z = FLIP1(L3.z, s3.z); o3.w = FLIP1(L3.w, s3.w);
        __builtin_nontemporal_store(o0, &out4[t0]);
        __builtin_nontemporal_store(o1, &out4[t0 + FLAT_THREADS]);
        __builtin_nontemporal_store(o2, &out4[t0 + 2 * FLAT_THREADS]);
        __builtin_nontemporal_store(o3, &out4[t0 + 3 * FLAT_THREADS]);
    }
#undef FLIP1
}

extern "C" void kernel_launch(void* const* d_in, const int* in_sizes, int n_in,
                              void* d_out, int out_size, void* d_ws, size_t ws_size,
                              hipStream_t stream) {
    const float* spins  = (const float*)d_in[0];
    const int*   labels = (const int*)d_in[1];
    const float* coins  = (const float*)d_in[2];
    float*       out    = (float*)d_out;

    // workspace layout (~5.2 MB total)
    char* ws = (char*)d_ws;
    int*      first_idx  = (int*)ws;                                   // 1 MB
    unsigned* bitmap     = (unsigned*)(ws + (1u << 20));               // 2 MB
    int*      wordPrefix = (int*)(ws + 3u * (1u << 20));               // 2 MB
    int*      chunkSums  = (int*)(ws + 5u * (1u << 20));               // 8 KB
    unsigned* seen       = (unsigned*)(ws + 5u*(1u<<20) + (1u<<15));   // 32 KB
    unsigned* flipbits   = (unsigned*)(ws + 5u*(1u<<20) + 2u*(1u<<15)); // 32 KB

    k_init<<<N_LABELS / 256, 256, 0, stream>>>(first_idx);
    k_seed_blind<<<SEED_BLOCKS + ZERO_BLOCKS, SEED_TPB, 0, stream>>>(
        (const int4*)labels, first_idx, (uint4*)bitmap);
    k_seen<<<N_LABELS / 256, 256, 0, stream>>>(first_idx, seen);
    k_first_flat<<<FLAT_BLOCKS, FLAT_TPB, 0, stream>>>((const int4*)labels, first_idx, seen);
    k_scatter<<<N_LABELS / 256, 256, 0, stream>>>(first_idx, bitmap);
    k_chunk_sums<<<NCHUNKS, WPC, 0, stream>>>(bitmap, chunkSums);
    k_word_prefix<<<NCHUNKS, WPC, 0, stream>>>(bitmap, chunkSums, wordPrefix);
    k_rank_flip<<<N_LABELS / 256, 256, 0, stream>>>(first_idx, bitmap, wordPrefix, coins, flipbits);
    k_out<<<FLAT_BLOCKS, FLAT_TPB, 0, stream>>>((const int4*)labels, (const float*)spins,
                                                flipbits, (float*)out);
}